// Round 2
// baseline (850.300 us; speedup 1.0000x reference)
//
#include <hip/hip_runtime.h>
#include <hip/hip_bf16.h>

typedef __bf16 bf16x8 __attribute__((ext_vector_type(8)));
typedef float  f32x4  __attribute__((ext_vector_type(4)));

#define N_ROWS 16384          // B*T
#define DDIM   4096
#define KPROT  256
#define BM     32
#define BK     64
#define OUT0_ELEMS 67108864   // 4*4096*4096

// ws layout (bytes)
#define WS_PB    0            // p_norm bf16, 256*4096*2 = 2 MB
#define WS_INV   2097152      // inv_norm, 256*4
#define WS_CSUM  2098176      // colsum, 4096*4
#define WS_CELL  2114560      // argmax cell, 8 B

__device__ __forceinline__ unsigned f2bf2(float lo, float hi) {
    unsigned a = __float_as_uint(lo), b = __float_as_uint(hi);
    a = (a + 0x7FFFu + ((a >> 16) & 1u)) >> 16;
    b = (b + 0x7FFFu + ((b >> 16) & 1u)) >> 16;
    return a | (b << 16);
}

__device__ __forceinline__ float gelu_tanh(float y) {
    float z = 0.7978845608028654f * (y + 0.044715f * y * y * y);
    float t = __expf(2.f * z);                  // tanh(z) = 1 - 2/(e^{2z}+1)
    float th = 1.f - __fdividef(2.f, t + 1.f);
    return 0.5f * y * (1.f + th);
}

__device__ __forceinline__ float sigmoidf(float v) {
    return 1.f / (1.f + __expf(-v));
}

// ---------------- K1: p_norm (bf16) + inv_norm ----------------
__global__ void __launch_bounds__(256) prep_kernel(const float* __restrict__ emas,
                                                   unsigned* __restrict__ pb,
                                                   float* __restrict__ inv_norm) {
    const int k = blockIdx.x, t = threadIdx.x;
    const int lane = t & 63, w = t >> 6;
    const f32x4* er = (const f32x4*)(emas + (size_t)k * DDIM);
    f32x4 v[4];
    float ss = 0.f;
#pragma unroll
    for (int j = 0; j < 4; ++j) {
        v[j] = er[j * 256 + t];
        ss += v[j][0] * v[j][0] + v[j][1] * v[j][1] + v[j][2] * v[j][2] + v[j][3] * v[j][3];
    }
#pragma unroll
    for (int m = 1; m < 64; m <<= 1) ss += __shfl_xor(ss, m);
    __shared__ float red[4];
    if (lane == 0) red[w] = ss;
    __syncthreads();
    float tot = red[0] + red[1] + red[2] + red[3];
    float inv = 1.f / fmaxf(sqrtf(tot), 1e-12f);
    if (t == 0) inv_norm[k] = inv;
#pragma unroll
    for (int j = 0; j < 4; ++j) {
        uint2 p2;
        p2.x = f2bf2(v[j][0] * inv, v[j][1] * inv);
        p2.y = f2bf2(v[j][2] * inv, v[j][3] * inv);
        *(uint2*)(pb + (size_t)k * 2048 + (size_t)(j * 256 + t) * 2) = p2;
    }
}

// ---------------- K2: fused sim-GEMM + rowmax + gelu + colsum ----------------
// LDS layout is XOR-swizzled: plane kc stores row-slot (n ^ kc). This makes the
// staging writes (lanes sharing arow, varying kc) hit 8 distinct bank groups
// instead of 1 (was 8-way conflicted); MFMA reads (rr in low bits) stay
// conflict-free since n^kc keeps low-3-bit distinctness within 8-lane phases.
__global__ void __launch_bounds__(256, 2)
main_kernel(const float* __restrict__ x, const unsigned* __restrict__ pb,
            const float* __restrict__ log_tau, const float* __restrict__ log_blend,
            const float* __restrict__ logit_decay,
            float* __restrict__ outp, float* __restrict__ colsum) {
    __shared__ __align__(16) unsigned lds_a[8 * BM * 4];     // 4 KB
    __shared__ __align__(16) unsigned lds_b[8 * KPROT * 4];  // 32 KB
    __shared__ float lds_wmax[4][BM];
    __shared__ float lds_sumsq[BM];
    __shared__ float lds_scale[BM];

    const int t = threadIdx.x;
    const int lane = t & 63, w = t >> 6;
    const int q = lane >> 4, rr = lane & 15;
    const int arow = t >> 3, ac = t & 7;     // staging: row in [0,32), chunk col in [0,8)
    const size_t row0 = (size_t)blockIdx.x * BM;

    const f32x4 zero = {0.f, 0.f, 0.f, 0.f};
    f32x4 acc[2][4];
#pragma unroll
    for (int rt = 0; rt < 2; ++rt)
#pragma unroll
        for (int ct = 0; ct < 4; ++ct) acc[rt][ct] = zero;

    float ss = 0.f;
    const float* xrow = x + (row0 + (size_t)arow) * DDIM + ac * 4;
    const unsigned* pbbase = pb + (size_t)arow * 2048 + ac * 4;

    // ---- software-pipeline: prefetch iteration 0 into registers
    f32x4 va = __builtin_nontemporal_load((const f32x4*)(xrow));
    f32x4 vb = __builtin_nontemporal_load((const f32x4*)(xrow + 32));
    int4 gb[8];
#pragma unroll
    for (int i = 0; i < 8; ++i)
        gb[i] = *(const int4*)(pbbase + (size_t)i * 65536);

    for (int it = 0; it < DDIM / BK; ++it) {
        // ---- stage A (fp32 -> bf16) + fused row sumsq, from prefetched regs
        ss += va[0] * va[0] + va[1] * va[1] + va[2] * va[2] + va[3] * va[3];
        ss += vb[0] * vb[0] + vb[1] * vb[1] + vb[2] * vb[2] + vb[3] * vb[3];
        uint2 pa, pbv;
        pa.x = f2bf2(va[0], va[1]);  pa.y = f2bf2(va[2], va[3]);
        pbv.x = f2bf2(vb[0], vb[1]); pbv.y = f2bf2(vb[2], vb[3]);
        const int kca = ac >> 1, kcb = kca + 4;
        *(uint2*)&lds_a[kca * 128 + ((arow ^ kca) * 4) + (ac & 1) * 2] = pa;
        *(uint2*)&lds_a[kcb * 128 + ((arow ^ kcb) * 4) + (ac & 1) * 2] = pbv;
        // ---- stage B (bf16 passthrough), swizzled row slot
#pragma unroll
        for (int i = 0; i < 8; ++i) {
            const int n = arow + i * 32;
            *(int4*)&lds_b[ac * 1024 + ((n ^ ac) * 4)] = gb[i];
        }
        __syncthreads();
        // ---- prefetch next iteration (hidden under MFMA + ds_read phase)
        if (it + 1 < DDIM / BK) {
            const int k0n = (it + 1) * BK;
            va = __builtin_nontemporal_load((const f32x4*)(xrow + k0n));
            vb = __builtin_nontemporal_load((const f32x4*)(xrow + k0n + 32));
#pragma unroll
            for (int i = 0; i < 8; ++i)
                gb[i] = *(const int4*)(pbbase + (size_t)i * 65536 + (it + 1) * 32);
        }
        // ---- MFMA: 2 row-tiles x 4 col-tiles per wave, 2 k-steps
#pragma unroll
        for (int ks8 = 0; ks8 < 8; ks8 += 4) {
            const int kcq = ks8 + q;
            bf16x8 af[2], bfr[4];
            af[0] = *(const bf16x8*)&lds_a[kcq * 128 + ((rr ^ kcq) * 4)];
            af[1] = *(const bf16x8*)&lds_a[kcq * 128 + (((16 + rr) ^ kcq) * 4)];
#pragma unroll
            for (int ct = 0; ct < 4; ++ct) {
                const int n = w * 64 + ct * 16 + rr;
                bfr[ct] = *(const bf16x8*)&lds_b[kcq * 1024 + ((n ^ kcq) * 4)];
            }
#pragma unroll
            for (int rt = 0; rt < 2; ++rt)
#pragma unroll
                for (int ct = 0; ct < 4; ++ct)
                    acc[rt][ct] = __builtin_amdgcn_mfma_f32_16x16x32_bf16(
                        af[rt], bfr[ct], acc[rt][ct], 0, 0, 0);
        }
        __syncthreads();
    }

    // ---- row sumsq: reduce over the 8 staging lanes of each row
    ss += __shfl_xor(ss, 1); ss += __shfl_xor(ss, 2); ss += __shfl_xor(ss, 4);
    if (ac == 0) lds_sumsq[arow] = ss;

    // ---- per-row max over this wave's 64 columns
#pragma unroll
    for (int rt = 0; rt < 2; ++rt)
#pragma unroll
        for (int i = 0; i < 4; ++i) {
            float m = fmaxf(fmaxf(acc[rt][0][i], acc[rt][1][i]),
                            fmaxf(acc[rt][2][i], acc[rt][3][i]));
            m = fmaxf(m, __shfl_xor(m, 1));
            m = fmaxf(m, __shfl_xor(m, 2));
            m = fmaxf(m, __shfl_xor(m, 4));
            m = fmaxf(m, __shfl_xor(m, 8));
            if (rr == 0) lds_wmax[w][rt * 16 + q * 4 + i] = m;
        }
    __syncthreads();

    if (t < BM) {
        float m = fmaxf(fmaxf(lds_wmax[0][t], lds_wmax[1][t]),
                        fmaxf(lds_wmax[2][t], lds_wmax[3][t]));
        float nrm = fmaxf(sqrtf(lds_sumsq[t]), 1e-12f);
        float msim = m / nrm;
        float tau = __expf(log_tau[0]);
        float ad = sigmoidf(log_blend[0]) * sigmoidf(logit_decay[0]);
        lds_scale[t] = 1.f - ad + ad * __expf(-tau * msim);
    }
    __syncthreads();

    // ---- epilogue: out = gelu(x*scale), fused column partial sums
    float cs[4][4];
#pragma unroll
    for (int j = 0; j < 4; ++j)
#pragma unroll
        for (int e = 0; e < 4; ++e) cs[j][e] = 0.f;

    for (int r = 0; r < BM; ++r) {
        const float s = lds_scale[r];
        const f32x4* xr = (const f32x4*)(x + (row0 + (size_t)r) * DDIM);
        f32x4* orow = (f32x4*)(outp + (row0 + (size_t)r) * DDIM);
#pragma unroll
        for (int j = 0; j < 4; ++j) {
            f32x4 v = __builtin_nontemporal_load(&xr[j * 256 + t]);
            cs[j][0] += v[0]; cs[j][1] += v[1]; cs[j][2] += v[2]; cs[j][3] += v[3];
            f32x4 g;
            g[0] = gelu_tanh(v[0] * s); g[1] = gelu_tanh(v[1] * s);
            g[2] = gelu_tanh(v[2] * s); g[3] = gelu_tanh(v[3] * s);
            __builtin_nontemporal_store(g, &orow[j * 256 + t]);
        }
    }
#pragma unroll
    for (int j = 0; j < 4; ++j)
#pragma unroll
        for (int e = 0; e < 4; ++e)
            atomicAdd(&colsum[j * 1024 + t * 4 + e], cs[j][e]);
}

// ---------------- K3: argmax_k dot(emas_k, colsum)*inv_norm_k ----------------
__global__ void __launch_bounds__(256) argmax_kernel(const float* __restrict__ emas,
                                                     const float* __restrict__ colsum,
                                                     const float* __restrict__ inv_norm,
                                                     unsigned long long* __restrict__ cell) {
    const int k = blockIdx.x, t = threadIdx.x;
    const int lane = t & 63, w = t >> 6;
    const f32x4* er = (const f32x4*)(emas + (size_t)k * DDIM);
    const f32x4* cr = (const f32x4*)colsum;
    float s = 0.f;
#pragma unroll
    for (int j = 0; j < 4; ++j) {
        f32x4 a = er[j * 256 + t], b = cr[j * 256 + t];
        s += a[0] * b[0] + a[1] * b[1] + a[2] * b[2] + a[3] * b[3];
    }
#pragma unroll
    for (int m = 1; m < 64; m <<= 1) s += __shfl_xor(s, m);
    __shared__ float red[4];
    if (lane == 0) red[w] = s;
    __syncthreads();
    if (t == 0) {
        float dotv = (red[0] + red[1] + red[2] + red[3]) * inv_norm[k];
        unsigned u = __float_as_uint(dotv);
        unsigned key = (u & 0x80000000u) ? ~u : (u | 0x80000000u);
        unsigned long long pk = ((unsigned long long)key << 32) |
                                (unsigned long long)(unsigned)(~k);
        atomicMax(cell, pk);
    }
}

// ---------------- K4: new_emas = emas with row k* blended ----------------
__global__ void __launch_bounds__(256) final_kernel(const float* __restrict__ emas,
                                                    const float* __restrict__ colsum,
                                                    const unsigned long long* __restrict__ cell,
                                                    const float* __restrict__ logit_decay,
                                                    float* __restrict__ out2) {
    const int idx = blockIdx.x * 256 + threadIdx.x;
    const int e = idx * 4;
    const int k = e >> 12, d0 = e & 4095;
    f32x4 v = *(const f32x4*)(emas + e);
    const unsigned kstar = ~(unsigned)(*cell);
    if ((unsigned)k == kstar) {
        const float dd = sigmoidf(logit_decay[0]);
        const float od = (1.f - dd) * (1.f / 16384.f);   // (1-d)/(B*T)
        f32x4 xm = *(const f32x4*)(colsum + d0);
        v[0] = dd * v[0] + od * xm[0];
        v[1] = dd * v[1] + od * xm[1];
        v[2] = dd * v[2] + od * xm[2];
        v[3] = dd * v[3] + od * xm[3];
    }
    *(f32x4*)(out2 + e) = v;
}

extern "C" void kernel_launch(void* const* d_in, const int* in_sizes, int n_in,
                              void* d_out, int out_size, void* d_ws, size_t ws_size,
                              hipStream_t stream) {
    const float* x           = (const float*)d_in[0];
    const float* emas        = (const float*)d_in[1];
    const float* log_tau     = (const float*)d_in[2];
    const float* log_blend   = (const float*)d_in[3];
    const float* logit_decay = (const float*)d_in[4];
    float* outp     = (float*)d_out;
    float* out_emas = outp + (size_t)OUT0_ELEMS;

    char* ws = (char*)d_ws;
    unsigned* pb                 = (unsigned*)(ws + WS_PB);
    float* inv_norm              = (float*)(ws + WS_INV);
    float* colsum                = (float*)(ws + WS_CSUM);
    unsigned long long* cell     = (unsigned long long*)(ws + WS_CELL);

    // zero colsum (16 KB) + argmax cell (contiguous)
    (void)hipMemsetAsync(colsum, 0, 16384 + 8, stream);

    prep_kernel<<<KPROT, 256, 0, stream>>>(emas, pb, inv_norm);
    main_kernel<<<N_ROWS / BM, 256, 0, stream>>>(x, pb, log_tau, log_blend,
                                                 logit_decay, outp, colsum);
    argmax_kernel<<<KPROT, 256, 0, stream>>>(emas, colsum, inv_norm, cell);
    final_kernel<<<KPROT * DDIM / 1024, 256, 0, stream>>>(emas, colsum, cell,
                                                          logit_decay, out_emas);
}

// Round 3
// 598.040 us; speedup vs baseline: 1.4218x; 1.4218x over previous
//
#include <hip/hip_runtime.h>
#include <hip/hip_bf16.h>

typedef __bf16 bf16x8 __attribute__((ext_vector_type(8)));
typedef float  f32x4  __attribute__((ext_vector_type(4)));

#define N_ROWS 16384          // B*T
#define DDIM   4096
#define KPROT  256
#define BM     32
#define BK     64
#define OUT0_ELEMS 67108864   // 4*4096*4096

// ws layout (bytes)
#define WS_PB    0            // p_norm bf16, 256*4096*2 = 2 MB
#define WS_INV   2097152      // inv_norm, 256*4
#define WS_CSUM  2098176      // colsum, 4096*4
#define WS_CELL  2114560      // argmax cell, 8 B

__device__ __forceinline__ unsigned f2bf2(float lo, float hi) {
    unsigned a = __float_as_uint(lo), b = __float_as_uint(hi);
    a = (a + 0x7FFFu + ((a >> 16) & 1u)) >> 16;
    b = (b + 0x7FFFu + ((b >> 16) & 1u)) >> 16;
    return a | (b << 16);
}

__device__ __forceinline__ float gelu_tanh(float y) {
    float z = 0.7978845608028654f * (y + 0.044715f * y * y * y);
    float t = __expf(2.f * z);                  // tanh(z) = 1 - 2/(e^{2z}+1)
    float th = 1.f - __fdividef(2.f, t + 1.f);
    return 0.5f * y * (1.f + th);
}

__device__ __forceinline__ float sigmoidf(float v) {
    return 1.f / (1.f + __expf(-v));
}

// ---------------- K1: p_norm (bf16) + inv_norm ----------------
__global__ void __launch_bounds__(256) prep_kernel(const float* __restrict__ emas,
                                                   unsigned* __restrict__ pb,
                                                   float* __restrict__ inv_norm) {
    const int k = blockIdx.x, t = threadIdx.x;
    const int lane = t & 63, w = t >> 6;
    const f32x4* er = (const f32x4*)(emas + (size_t)k * DDIM);
    f32x4 v[4];
    float ss = 0.f;
#pragma unroll
    for (int j = 0; j < 4; ++j) {
        v[j] = er[j * 256 + t];
        ss += v[j][0] * v[j][0] + v[j][1] * v[j][1] + v[j][2] * v[j][2] + v[j][3] * v[j][3];
    }
#pragma unroll
    for (int m = 1; m < 64; m <<= 1) ss += __shfl_xor(ss, m);
    __shared__ float red[4];
    if (lane == 0) red[w] = ss;
    __syncthreads();
    float tot = red[0] + red[1] + red[2] + red[3];
    float inv = 1.f / fmaxf(sqrtf(tot), 1e-12f);
    if (t == 0) inv_norm[k] = inv;
#pragma unroll
    for (int j = 0; j < 4; ++j) {
        uint2 p2;
        p2.x = f2bf2(v[j][0] * inv, v[j][1] * inv);
        p2.y = f2bf2(v[j][2] * inv, v[j][3] * inv);
        *(uint2*)(pb + (size_t)k * 2048 + (size_t)(j * 256 + t) * 2) = p2;
    }
}

// ---------------- K2: fused sim-GEMM + rowmax + gelu + colsum ----------------
// LDS layout is XOR-swizzled: plane kc stores row-slot (n ^ kc). Staging writes
// (lanes sharing arow, varying kc) hit 8 distinct bank groups instead of 1;
// MFMA reads stay conflict-free (rr low bits remain distinct under ^kcq).
// Verified round 1->2: SQ_LDS_BANK_CONFLICT 6.2e7 -> 1.0e6.
// NOTE: no register prefetch of next tile — the gb[8] pipeline spilled to
// scratch (WRITE_SIZE 295->837 MB, +210us). Loads stage directly to LDS.
__global__ void __launch_bounds__(256, 2)
main_kernel(const float* __restrict__ x, const unsigned* __restrict__ pb,
            const float* __restrict__ log_tau, const float* __restrict__ log_blend,
            const float* __restrict__ logit_decay,
            float* __restrict__ outp, float* __restrict__ colsum) {
    __shared__ __align__(16) unsigned lds_a[8 * BM * 4];     // 4 KB
    __shared__ __align__(16) unsigned lds_b[8 * KPROT * 4];  // 32 KB
    __shared__ float lds_wmax[4][BM];
    __shared__ float lds_sumsq[BM];
    __shared__ float lds_scale[BM];

    const int t = threadIdx.x;
    const int lane = t & 63, w = t >> 6;
    const int q = lane >> 4, rr = lane & 15;
    const int arow = t >> 3, ac = t & 7;     // staging: row in [0,32), chunk col in [0,8)
    const size_t row0 = (size_t)blockIdx.x * BM;

    const f32x4 zero = {0.f, 0.f, 0.f, 0.f};
    f32x4 acc[2][4];
#pragma unroll
    for (int rt = 0; rt < 2; ++rt)
#pragma unroll
        for (int ct = 0; ct < 4; ++ct) acc[rt][ct] = zero;

    float ss = 0.f;
    const float* xrow = x + (row0 + (size_t)arow) * DDIM + ac * 4;
    const unsigned* pbbase = pb + (size_t)arow * 2048 + ac * 4;

    for (int it = 0; it < DDIM / BK; ++it) {
        const int k0 = it * BK;
        // ---- stage A (fp32 -> bf16) + fused row sumsq
        f32x4 va = __builtin_nontemporal_load((const f32x4*)(xrow + k0));
        f32x4 vb = __builtin_nontemporal_load((const f32x4*)(xrow + k0 + 32));
        ss += va[0] * va[0] + va[1] * va[1] + va[2] * va[2] + va[3] * va[3];
        ss += vb[0] * vb[0] + vb[1] * vb[1] + vb[2] * vb[2] + vb[3] * vb[3];
        uint2 pa, pbv;
        pa.x = f2bf2(va[0], va[1]);  pa.y = f2bf2(va[2], va[3]);
        pbv.x = f2bf2(vb[0], vb[1]); pbv.y = f2bf2(vb[2], vb[3]);
        const int kca = ac >> 1, kcb = kca + 4;
        *(uint2*)&lds_a[kca * 128 + ((arow ^ kca) * 4) + (ac & 1) * 2] = pa;
        *(uint2*)&lds_a[kcb * 128 + ((arow ^ kcb) * 4) + (ac & 1) * 2] = pbv;
        // ---- stage B (bf16 passthrough), swizzled row slot
#pragma unroll
        for (int i = 0; i < 8; ++i) {
            const int n = arow + i * 32;
            int4 g = *(const int4*)(pbbase + (size_t)i * 65536 + it * 32);
            *(int4*)&lds_b[ac * 1024 + ((n ^ ac) * 4)] = g;
        }
        __syncthreads();
        // ---- MFMA: 2 row-tiles x 4 col-tiles per wave, 2 k-steps
#pragma unroll
        for (int ks8 = 0; ks8 < 8; ks8 += 4) {
            const int kcq = ks8 + q;
            bf16x8 af[2], bfr[4];
            af[0] = *(const bf16x8*)&lds_a[kcq * 128 + ((rr ^ kcq) * 4)];
            af[1] = *(const bf16x8*)&lds_a[kcq * 128 + (((16 + rr) ^ kcq) * 4)];
#pragma unroll
            for (int ct = 0; ct < 4; ++ct) {
                const int n = w * 64 + ct * 16 + rr;
                bfr[ct] = *(const bf16x8*)&lds_b[kcq * 1024 + ((n ^ kcq) * 4)];
            }
#pragma unroll
            for (int rt = 0; rt < 2; ++rt)
#pragma unroll
                for (int ct = 0; ct < 4; ++ct)
                    acc[rt][ct] = __builtin_amdgcn_mfma_f32_16x16x32_bf16(
                        af[rt], bfr[ct], acc[rt][ct], 0, 0, 0);
        }
        __syncthreads();
    }

    // ---- row sumsq: reduce over the 8 staging lanes of each row
    ss += __shfl_xor(ss, 1); ss += __shfl_xor(ss, 2); ss += __shfl_xor(ss, 4);
    if (ac == 0) lds_sumsq[arow] = ss;

    // ---- per-row max over this wave's 64 columns
#pragma unroll
    for (int rt = 0; rt < 2; ++rt)
#pragma unroll
        for (int i = 0; i < 4; ++i) {
            float m = fmaxf(fmaxf(acc[rt][0][i], acc[rt][1][i]),
                            fmaxf(acc[rt][2][i], acc[rt][3][i]));
            m = fmaxf(m, __shfl_xor(m, 1));
            m = fmaxf(m, __shfl_xor(m, 2));
            m = fmaxf(m, __shfl_xor(m, 4));
            m = fmaxf(m, __shfl_xor(m, 8));
            if (rr == 0) lds_wmax[w][rt * 16 + q * 4 + i] = m;
        }
    __syncthreads();

    if (t < BM) {
        float m = fmaxf(fmaxf(lds_wmax[0][t], lds_wmax[1][t]),
                        fmaxf(lds_wmax[2][t], lds_wmax[3][t]));
        float nrm = fmaxf(sqrtf(lds_sumsq[t]), 1e-12f);
        float msim = m / nrm;
        float tau = __expf(log_tau[0]);
        float ad = sigmoidf(log_blend[0]) * sigmoidf(logit_decay[0]);
        lds_scale[t] = 1.f - ad + ad * __expf(-tau * msim);
    }
    __syncthreads();

    // ---- epilogue: out = gelu(x*scale), fused column partial sums
    float cs[4][4];
#pragma unroll
    for (int j = 0; j < 4; ++j)
#pragma unroll
        for (int e = 0; e < 4; ++e) cs[j][e] = 0.f;

    for (int r = 0; r < BM; ++r) {
        const float s = lds_scale[r];
        const f32x4* xr = (const f32x4*)(x + (row0 + (size_t)r) * DDIM);
        f32x4* orow = (f32x4*)(outp + (row0 + (size_t)r) * DDIM);
#pragma unroll
        for (int j = 0; j < 4; ++j) {
            f32x4 v = __builtin_nontemporal_load(&xr[j * 256 + t]);
            cs[j][0] += v[0]; cs[j][1] += v[1]; cs[j][2] += v[2]; cs[j][3] += v[3];
            f32x4 g;
            g[0] = gelu_tanh(v[0] * s); g[1] = gelu_tanh(v[1] * s);
            g[2] = gelu_tanh(v[2] * s); g[3] = gelu_tanh(v[3] * s);
            __builtin_nontemporal_store(g, &orow[j * 256 + t]);
        }
    }
#pragma unroll
    for (int j = 0; j < 4; ++j)
#pragma unroll
        for (int e = 0; e < 4; ++e)
            atomicAdd(&colsum[j * 1024 + t * 4 + e], cs[j][e]);
}

// ---------------- K3: argmax_k dot(emas_k, colsum)*inv_norm_k ----------------
__global__ void __launch_bounds__(256) argmax_kernel(const float* __restrict__ emas,
                                                     const float* __restrict__ colsum,
                                                     const float* __restrict__ inv_norm,
                                                     unsigned long long* __restrict__ cell) {
    const int k = blockIdx.x, t = threadIdx.x;
    const int lane = t & 63, w = t >> 6;
    const f32x4* er = (const f32x4*)(emas + (size_t)k * DDIM);
    const f32x4* cr = (const f32x4*)colsum;
    float s = 0.f;
#pragma unroll
    for (int j = 0; j < 4; ++j) {
        f32x4 a = er[j * 256 + t], b = cr[j * 256 + t];
        s += a[0] * b[0] + a[1] * b[1] + a[2] * b[2] + a[3] * b[3];
    }
#pragma unroll
    for (int m = 1; m < 64; m <<= 1) s += __shfl_xor(s, m);
    __shared__ float red[4];
    if (lane == 0) red[w] = s;
    __syncthreads();
    if (t == 0) {
        float dotv = (red[0] + red[1] + red[2] + red[3]) * inv_norm[k];
        unsigned u = __float_as_uint(dotv);
        unsigned key = (u & 0x80000000u) ? ~u : (u | 0x80000000u);
        unsigned long long pk = ((unsigned long long)key << 32) |
                                (unsigned long long)(unsigned)(~k);
        atomicMax(cell, pk);
    }
}

// ---------------- K4: new_emas = emas with row k* blended ----------------
__global__ void __launch_bounds__(256) final_kernel(const float* __restrict__ emas,
                                                    const float* __restrict__ colsum,
                                                    const unsigned long long* __restrict__ cell,
                                                    const float* __restrict__ logit_decay,
                                                    float* __restrict__ out2) {
    const int idx = blockIdx.x * 256 + threadIdx.x;
    const int e = idx * 4;
    const int k = e >> 12, d0 = e & 4095;
    f32x4 v = *(const f32x4*)(emas + e);
    const unsigned kstar = ~(unsigned)(*cell);
    if ((unsigned)k == kstar) {
        const float dd = sigmoidf(logit_decay[0]);
        const float od = (1.f - dd) * (1.f / 16384.f);   // (1-d)/(B*T)
        f32x4 xm = *(const f32x4*)(colsum + d0);
        v[0] = dd * v[0] + od * xm[0];
        v[1] = dd * v[1] + od * xm[1];
        v[2] = dd * v[2] + od * xm[2];
        v[3] = dd * v[3] + od * xm[3];
    }
    *(f32x4*)(out2 + e) = v;
}

extern "C" void kernel_launch(void* const* d_in, const int* in_sizes, int n_in,
                              void* d_out, int out_size, void* d_ws, size_t ws_size,
                              hipStream_t stream) {
    const float* x           = (const float*)d_in[0];
    const float* emas        = (const float*)d_in[1];
    const float* log_tau     = (const float*)d_in[2];
    const float* log_blend   = (const float*)d_in[3];
    const float* logit_decay = (const float*)d_in[4];
    float* outp     = (float*)d_out;
    float* out_emas = outp + (size_t)OUT0_ELEMS;

    char* ws = (char*)d_ws;
    unsigned* pb                 = (unsigned*)(ws + WS_PB);
    float* inv_norm              = (float*)(ws + WS_INV);
    float* colsum                = (float*)(ws + WS_CSUM);
    unsigned long long* cell     = (unsigned long long*)(ws + WS_CELL);

    // zero colsum (16 KB) + argmax cell (contiguous)
    (void)hipMemsetAsync(colsum, 0, 16384 + 8, stream);

    prep_kernel<<<KPROT, 256, 0, stream>>>(emas, pb, inv_norm);
    main_kernel<<<N_ROWS / BM, 256, 0, stream>>>(x, pb, log_tau, log_blend,
                                                 logit_decay, outp, colsum);
    argmax_kernel<<<KPROT, 256, 0, stream>>>(emas, colsum, inv_norm, cell);
    final_kernel<<<KPROT * DDIM / 1024, 256, 0, stream>>>(emas, colsum, cell,
                                                          logit_decay, out_emas);
}